// Round 3
// baseline (85.992 us; speedup 1.0000x reference)
//
#include <hip/hip_runtime.h>

#define NBODY 8192
#define BLOCK 256
#define IPT 2                       // i-bodies per thread
#define ITILE (BLOCK * IPT)         // 512
#define NITILES (NBODY / ITILE)     // 16
#define SLABS 128                   // j-slabs
#define JCHUNK (NBODY / SLABS)      // 64 j-bodies per slab
#define NF (NBODY * 3)              // 24576 output floats
#define SOFT2 1.0e-4f               // 0.01^2

// grid (16, 128) = 2048 blocks = 8 blocks/CU = 8 waves/SIMD (max occupancy).
// R0/R2 both ran 4 waves/SIMD and both landed at ~37us force regardless of
// DS traffic or per-wave ILP -> stall-bound (SIMD idle ~60%). This round's
// single lever: 2x resident waves to cover the dep-chain + rsq-latency
// bubbles. __launch_bounds__(256,8) caps VGPR at 64 so 8 waves/SIMD fit.
__global__ __launch_bounds__(BLOCK, 8) void force_kernel(
    const float* __restrict__ pos, const float* __restrict__ mass,
    float* __restrict__ part) {
  __shared__ float4 tile[JCHUNK];

  const int t = threadIdx.x;
  const int j0 = blockIdx.y * JCHUNK;
  if (t < JCHUNK) {
    const int j = j0 + t;
    tile[t] =
        make_float4(pos[j * 3 + 0], pos[j * 3 + 1], pos[j * 3 + 2], mass[j]);
  }

  const int i1 = blockIdx.x * ITILE + t;
  const int i2 = i1 + BLOCK;
  const float x1 = pos[i1 * 3 + 0];
  const float y1 = pos[i1 * 3 + 1];
  const float z1 = pos[i1 * 3 + 2];
  const float x2 = pos[i2 * 3 + 0];
  const float y2 = pos[i2 * 3 + 1];
  const float z2 = pos[i2 * 3 + 2];

  float ax1 = 0.f, ay1 = 0.f, az1 = 0.f;
  float ax2 = 0.f, ay2 = 0.f, az2 = 0.f;

  __syncthreads();

  // unroll 4 keeps live tile values at 16 VGPR so the wave fits in 64.
#pragma unroll 4
  for (int k = 0; k < JCHUNK; ++k) {
    const float4 o = tile[k];  // wave-uniform ds_read_b128 broadcast
    float dx1 = o.x - x1, dy1 = o.y - y1, dz1 = o.z - z1;
    float dx2 = o.x - x2, dy2 = o.y - y2, dz2 = o.z - z2;
    float r21 = fmaf(dx1, dx1, fmaf(dy1, dy1, fmaf(dz1, dz1, SOFT2)));
    float r22 = fmaf(dx2, dx2, fmaf(dy2, dy2, fmaf(dz2, dz2, SOFT2)));
    float in1 = __builtin_amdgcn_rsqf(r21);  // v_rsq_f32
    float in2 = __builtin_amdgcn_rsqf(r22);
    float w1 = o.w * (in1 * in1 * in1);      // m_j * r^-3
    float w2 = o.w * (in2 * in2 * in2);
    ax1 = fmaf(w1, dx1, ax1);
    ay1 = fmaf(w1, dy1, ay1);
    az1 = fmaf(w1, dz1, az1);
    ax2 = fmaf(w2, dx2, ax2);
    ay2 = fmaf(w2, dy2, ay2);
    az2 = fmaf(w2, dz2, az2);
  }

  // SoA partials [slab][comp][body]: fully coalesced stores, no contention.
  float* __restrict__ dst = part + (size_t)blockIdx.y * NF;
  dst[0 * NBODY + i1] = ax1;
  dst[1 * NBODY + i1] = ay1;
  dst[2 * NBODY + i1] = az1;
  dst[0 * NBODY + i2] = ax2;
  dst[1 * NBODY + i2] = ay2;
  dst[2 * NBODY + i2] = az2;
}

// grid (96, 4): block (bx, g) sums slabs [g*32, g*32+32) for 256 outputs,
// then one atomicAdd per thread (4-way contention, trivial). 384 blocks
// instead of R2's 96 -> ~3x the streaming coverage, ~2us.
__global__ __launch_bounds__(BLOCK) void reduce_kernel(
    const float* __restrict__ part, float* __restrict__ out) {
  const int idx = blockIdx.x * BLOCK + threadIdx.x;  // SoA index < NF
  const int c = idx >> 13;          // component (idx / NBODY)
  const int b = idx & (NBODY - 1);  // body
  const int sl0 = blockIdx.y * (SLABS / 4);
  float s0 = 0.f, s1 = 0.f, s2 = 0.f, s3 = 0.f;
#pragma unroll 8
  for (int sl = 0; sl < SLABS / 4; sl += 4) {
    s0 += part[(size_t)(sl0 + sl + 0) * NF + idx];
    s1 += part[(size_t)(sl0 + sl + 1) * NF + idx];
    s2 += part[(size_t)(sl0 + sl + 2) * NF + idx];
    s3 += part[(size_t)(sl0 + sl + 3) * NF + idx];
  }
  atomicAdd(&out[b * 3 + c], (s0 + s1) + (s2 + s3));
}

extern "C" void kernel_launch(void* const* d_in, const int* in_sizes, int n_in,
                              void* d_out, int out_size, void* d_ws,
                              size_t ws_size, hipStream_t stream) {
  const float* pos = (const float*)d_in[0];
  const float* mass = (const float*)d_in[1];
  float* out = (float*)d_out;
  float* part = (float*)d_ws;  // 128 * 24576 * 4 B = 12.6 MB

  // d_out is re-poisoned before each launch; atomics in reduce need zeros.
  hipMemsetAsync(d_out, 0, (size_t)out_size * sizeof(float), stream);

  force_kernel<<<dim3(NITILES, SLABS), BLOCK, 0, stream>>>(pos, mass, part);
  reduce_kernel<<<dim3(NF / BLOCK, 4), BLOCK, 0, stream>>>(part, out);
}

// Round 4
// 82.940 us; speedup vs baseline: 1.0368x; 1.0368x over previous
//
#include <hip/hip_runtime.h>

#define NBODY 8192
#define BLOCK 256
#define IPT 4                       // i-bodies per thread
#define ITILE (BLOCK * IPT)         // 1024
#define NITILES (NBODY / ITILE)     // 8
#define SLABS 128                   // j-slabs
#define JCHUNK (NBODY / SLABS)      // 64 j-bodies per slab
#define PHASE 16                    // j-bodies register-hoisted per phase
#define NPHASE (JCHUNK / PHASE)     // 4
#define NF (NBODY * 3)              // 24576 output floats
#define SOFT2 1.0e-4f               // 0.01^2

// R0/R2/R3 established: force time (~38us) is invariant to occupancy (4 or 8
// waves/SIMD), per-wave ILP (IPT 1/2/4), DS traffic, and packed math. The one
// untried scheduling lever: remove the in-loop dependent LDS broadcast. Here
// each phase hoists 16 float4 j-bodies LDS->VGPR in one burst (16 independent
// ds_read_b128, ONE lgkm wait ~300cy), then computes 64 pairs (~1650cy) from
// registers only. DS latency moves off the per-unroll-group critical path.
// IPT=4 keeps per-CU DS-pipe demand ~46% (at IPT=2 the 4 SIMDs' broadcasts
// oversubscribe the shared DS pipe ~2x).
__global__ __launch_bounds__(BLOCK, 4) void force_kernel(
    const float* __restrict__ pos, const float* __restrict__ mass,
    float* __restrict__ part) {
  __shared__ float4 tile[JCHUNK];

  const int t = threadIdx.x;
  const int j0 = blockIdx.y * JCHUNK;
  if (t < JCHUNK) {
    const int j = j0 + t;
    tile[t] =
        make_float4(pos[j * 3 + 0], pos[j * 3 + 1], pos[j * 3 + 2], mass[j]);
  }

  const int ib = blockIdx.x * ITILE + t;  // i-bodies: ib + p*BLOCK
  float xi[IPT], yi[IPT], zi[IPT];
  float ax[IPT], ay[IPT], az[IPT];
#pragma unroll
  for (int p = 0; p < IPT; ++p) {
    const int i = ib + p * BLOCK;
    xi[p] = pos[i * 3 + 0];
    yi[p] = pos[i * 3 + 1];
    zi[p] = pos[i * 3 + 2];
    ax[p] = 0.f;
    ay[p] = 0.f;
    az[p] = 0.f;
  }

  __syncthreads();

  for (int c = 0; c < NPHASE; ++c) {
    // Burst-hoist one phase of j-bodies into registers (64 VGPR). All 16
    // ds_read_b128 are independent -> issued back-to-back, single wait.
    float4 jt[PHASE];
#pragma unroll
    for (int u = 0; u < PHASE; ++u) jt[u] = tile[c * PHASE + u];

    // Pure-register compute: 16 j x 4 i = 64 pairs, no memory deps.
#pragma unroll
    for (int u = 0; u < PHASE; ++u) {
#pragma unroll
      for (int p = 0; p < IPT; ++p) {
        float dx = jt[u].x - xi[p];
        float dy = jt[u].y - yi[p];
        float dz = jt[u].z - zi[p];
        float r2 = fmaf(dx, dx, fmaf(dy, dy, fmaf(dz, dz, SOFT2)));
        float inv = __builtin_amdgcn_rsqf(r2);  // v_rsq_f32
        float w = jt[u].w * (inv * inv * inv);  // m_j * r^-3
        ax[p] = fmaf(w, dx, ax[p]);
        ay[p] = fmaf(w, dy, ay[p]);
        az[p] = fmaf(w, dz, az[p]);
      }
    }
  }

  // SoA partials [slab][comp][body]: fully coalesced stores, no contention.
  float* __restrict__ dst = part + (size_t)blockIdx.y * NF;
#pragma unroll
  for (int p = 0; p < IPT; ++p) {
    const int i = ib + p * BLOCK;
    dst[0 * NBODY + i] = ax[p];
    dst[1 * NBODY + i] = ay[p];
    dst[2 * NBODY + i] = az[p];
  }
}

// grid (96, 4): block (bx, g) sums slabs [g*32, g*32+32), one 4-way-contended
// atomicAdd per output element. ~2-3us.
__global__ __launch_bounds__(BLOCK) void reduce_kernel(
    const float* __restrict__ part, float* __restrict__ out) {
  const int idx = blockIdx.x * BLOCK + threadIdx.x;  // SoA index < NF
  const int c = idx >> 13;          // component (idx / NBODY)
  const int b = idx & (NBODY - 1);  // body
  const int sl0 = blockIdx.y * (SLABS / 4);
  float s0 = 0.f, s1 = 0.f, s2 = 0.f, s3 = 0.f;
#pragma unroll 8
  for (int sl = 0; sl < SLABS / 4; sl += 4) {
    s0 += part[(size_t)(sl0 + sl + 0) * NF + idx];
    s1 += part[(size_t)(sl0 + sl + 1) * NF + idx];
    s2 += part[(size_t)(sl0 + sl + 2) * NF + idx];
    s3 += part[(size_t)(sl0 + sl + 3) * NF + idx];
  }
  atomicAdd(&out[b * 3 + c], (s0 + s1) + (s2 + s3));
}

extern "C" void kernel_launch(void* const* d_in, const int* in_sizes, int n_in,
                              void* d_out, int out_size, void* d_ws,
                              size_t ws_size, hipStream_t stream) {
  const float* pos = (const float*)d_in[0];
  const float* mass = (const float*)d_in[1];
  float* out = (float*)d_out;
  float* part = (float*)d_ws;  // 128 * 24576 * 4 B = 12.6 MB

  // d_out is re-poisoned before each launch; atomics in reduce need zeros.
  hipMemsetAsync(d_out, 0, (size_t)out_size * sizeof(float), stream);

  force_kernel<<<dim3(NITILES, SLABS), BLOCK, 0, stream>>>(pos, mass, part);
  reduce_kernel<<<dim3(NF / BLOCK, 4), BLOCK, 0, stream>>>(part, out);
}